// Round 1
// baseline (725.924 us; speedup 1.0000x reference)
//
#include <hip/hip_runtime.h>

// CRF forward-algorithm partition function (log Z) per batch element.
// logits [B,S,L] f32, transitions [L,L] f32, lens [B] int32, out [B] f32.
// L = 128 fixed. One block per batch element, 128 threads; thread i owns
// exp(transitions[i][:]) in registers (32 float4, statically indexed).
//
// Recurrence rewritten as:
//   m = max_j alpha[j]
//   alpha'[i] = logit[i] + m + log( sum_j expT[i][j] * exp(alpha[j]-m) )
// which is mathematically identical to logsumexp over (T[i,j]+alpha[j])
// and numerically safe: exp(alpha-m) in (0,1], expT bounded (T ~ N(0,1)).

constexpr int L = 128;

__global__ __launch_bounds__(128, 2) void crf_fwd_kernel(
    const float* __restrict__ logits,
    const float* __restrict__ trans,
    const int* __restrict__ lens,
    float* __restrict__ out,
    int S)
{
    const int b    = blockIdx.x;
    const int tid  = threadIdx.x;      // 0..127, owns output row tid
    const int lane = tid & 63;
    const int wv   = tid >> 6;         // wave id within block (0 or 1)

    __shared__ float wlds[L];          // exp(alpha - m), broadcast source
    __shared__ float red[2];           // cross-wave reduction scratch

    // ---- one-time: expT row for this thread into registers ----
    float4 row[L / 4];
    {
        const float4* trow = reinterpret_cast<const float4*>(trans) + tid * (L / 4);
#pragma unroll
        for (int j = 0; j < L / 4; ++j) {
            float4 v = trow[j];
            row[j] = make_float4(__expf(v.x), __expf(v.y), __expf(v.z), __expf(v.w));
        }
    }

    float alpha = (tid == 0) ? 0.0f : -10000.0f;   // BOS_IDX = 0
    const int len = lens[b];                        // steps that actually update
    const float* lp = logits + (size_t)b * (size_t)S * L + tid;

    for (int t = 0; t < len; ++t) {
        float logit = lp[(size_t)t * L];           // coalesced, prefetches early

        // ---- m = max over all 128 alphas ----
        float m = alpha;
#pragma unroll
        for (int off = 32; off >= 1; off >>= 1)
            m = fmaxf(m, __shfl_xor(m, off, 64));
        if (lane == 0) red[wv] = m;
        __syncthreads();                           // red ready; prev wlds reads done
        m = fmaxf(red[0], red[1]);

        wlds[tid] = __expf(alpha - m);
        __syncthreads();                           // wlds ready; red reads done

        // ---- dot: sum_j expT[tid][j] * w[j] (broadcast LDS reads) ----
        float4 s4 = make_float4(0.f, 0.f, 0.f, 0.f);
        const float4* w4 = reinterpret_cast<const float4*>(wlds);
#pragma unroll
        for (int j = 0; j < L / 4; ++j) {
            float4 w = w4[j];
            s4.x = fmaf(row[j].x, w.x, s4.x);
            s4.y = fmaf(row[j].y, w.y, s4.y);
            s4.z = fmaf(row[j].z, w.z, s4.z);
            s4.w = fmaf(row[j].w, w.w, s4.w);
        }
        float sum = (s4.x + s4.y) + (s4.z + s4.w);

        alpha = logit + m + __logf(sum);
        // next iteration's red[] write is ordered by the first __syncthreads
    }

    // ---- final logsumexp over alpha[0..127] ----
    float m = alpha;
#pragma unroll
    for (int off = 32; off >= 1; off >>= 1)
        m = fmaxf(m, __shfl_xor(m, off, 64));
    __syncthreads();                               // retire last iter's wlds reads
    if (lane == 0) red[wv] = m;
    __syncthreads();
    m = fmaxf(red[0], red[1]);

    float e = __expf(alpha - m);
#pragma unroll
    for (int off = 32; off >= 1; off >>= 1)
        e += __shfl_xor(e, off, 64);
    __syncthreads();                               // red max-reads done
    if (lane == 0) red[wv] = e;
    __syncthreads();
    if (tid == 0) out[b] = m + __logf(red[0] + red[1]);
}

extern "C" void kernel_launch(void* const* d_in, const int* in_sizes, int n_in,
                              void* d_out, int out_size, void* d_ws, size_t ws_size,
                              hipStream_t stream)
{
    const float* logits = (const float*)d_in[0];
    const float* trans  = (const float*)d_in[1];
    const int*   lens   = (const int*)d_in[2];
    float*       out    = (float*)d_out;

    const int B = in_sizes[2];                 // lens element count
    const int S = in_sizes[0] / (B * L);       // logits = B*S*L

    crf_fwd_kernel<<<B, 128, 0, stream>>>(logits, trans, lens, out, S);
}